// Round 9
// baseline (473.722 us; speedup 1.0000x reference)
//
#include <hip/hip_runtime.h>
#include <hip/hip_bf16.h>
#include <stdint.h>

// Problem dims: B=4, S=2048 -> M=8192; IN=K=4096; OUT=N=4096; R=16
#define M_DIM 8192
#define N_DIM 4096
#define K_DIM 4096
#define R_DIM 16

typedef __bf16 bf16x8 __attribute__((ext_vector_type(8)));
typedef float f32x4 __attribute__((ext_vector_type(4)));
typedef unsigned short u16x8 __attribute__((ext_vector_type(8)));

#define AS1(p) ((const __attribute__((address_space(1))) void*)(p))
#define AS3(p) ((__attribute__((address_space(3))) void*)(p))

#define BAR() do { asm volatile("" ::: "memory"); __builtin_amdgcn_s_barrier(); asm volatile("" ::: "memory"); } while (0)
#define VMCNT4()  asm volatile("s_waitcnt vmcnt(4)" ::: "memory")
#define VMCNT0()  asm volatile("s_waitcnt vmcnt(0)" ::: "memory")
#define VMCNT12() asm volatile("s_waitcnt vmcnt(12)" ::: "memory")

__device__ __forceinline__ unsigned short f2bf(float f) {
  unsigned u = __builtin_bit_cast(unsigned, f);
  u += 0x7FFFu + ((u >> 16) & 1u);   // round-to-nearest-even
  return (unsigned short)(u >> 16);
}

// ---------------------------------------------------------------------------
// prep: blocks [0,1024): awb[o,i] = bf16(W[o,i]*(1+sum_r A[r,i]*B[o,r]))
//       blocks [1024,5120): xb = bf16(x), vectorized grid-stride
// ---------------------------------------------------------------------------
#define CVT_BLOCKS 4096
__global__ void __launch_bounds__(256) prep_kernel(
    const float* __restrict__ x, const float* __restrict__ W,
    const float* __restrict__ lA, const float* __restrict__ lB,
    unsigned short* __restrict__ xb, unsigned short* __restrict__ awb) {
  __shared__ float Asub[16 * 512];
  __shared__ float Bsub[32 * 16];
  const int tid = threadIdx.x;

  if (blockIdx.x < 1024) {
    const int i0 = (blockIdx.x & 7) * 512;
    const int o0 = (blockIdx.x >> 3) * 32;
    for (int idx = tid; idx < 16 * 512; idx += 256) {
      int r = idx >> 9, i = idx & 511;
      Asub[idx] = lA[r * K_DIM + i0 + i];
    }
    for (int idx = tid; idx < 32 * 16; idx += 256) {
      int o = idx >> 4, r = idx & 15;
      Bsub[idx] = lB[(o0 + o) * R_DIM + r];
    }
    __syncthreads();
    for (int idx = tid; idx < 32 * 512; idx += 256) {
      int o = idx >> 9, i = idx & 511;
      float s = 1.0f;
#pragma unroll
      for (int r = 0; r < 16; ++r) s += Asub[r * 512 + i] * Bsub[o * 16 + r];
      size_t g = (size_t)(o0 + o) * K_DIM + i0 + i;
      awb[g] = f2bf(W[g] * s);
    }
  } else {
    const long total = (long)M_DIM * K_DIM;
    long i = ((long)(blockIdx.x - 1024) * 256 + tid) * 8;
    const long stride = (long)CVT_BLOCKS * 256 * 8;
    for (; i < total; i += stride) {
      const float4* p = (const float4*)(x + i);
      float4 f0 = p[0], f1 = p[1];
      u16x8 v;
      v[0] = f2bf(f0.x); v[1] = f2bf(f0.y); v[2] = f2bf(f0.z); v[3] = f2bf(f0.w);
      v[4] = f2bf(f1.x); v[5] = f2bf(f1.y); v[6] = f2bf(f1.z); v[7] = f2bf(f1.w);
      *(u16x8*)(xb + i) = v;
    }
  }
}

// ---------------------------------------------------------------------------
// GEMM: out[m,n] = sum_k xb[m,k]*awb[n,k] + bias[n]
// 256x256 tile, BK=64, 8 waves (2Mx4N). KEY CHANGE (R9): B fragments load
// GLOBAL->VGPR directly (contiguous 16B/lane; full 128B-line use per kk-pair),
// taking B off the LDS pipe. LDS now carries A only: 128KB reads + 32KB gll
// writes = 160KB/K-tile (1882 cy) < MFMA (2483 cy) -- previously 256KB
// (3073 cy) > MFMA, which capped MfmaUtil at ~50% in R3-R8 regardless of
// schedule. B loads are WAR-in-place (0 extra VGPR; file is at the
// 2-wave/SIMD cliff: 128 VGPR + 128 AGPR acc), prefetched ~1 tile ahead.
// XCD swizzle flipped to column-major so same-XCD blocks share bcol ->
// B panel working set/XCD ~4MB ~ L2.
// Per tile t (buf=t&1, nx=buf^1; Q0:a_lo*blo Q1:a_lo*bhi Q2:a_hi*blo Q3:a_hi*bhi):
//  PhA: VMCNT4 [drains blo(t) + own A(t+1) glls; leaves bhi(t)=4] | Q0 |
//       VMCNT0 [drains bhi(t)] | Q1 | ds_read a_hi(t)<-buf | BAR(mid)
//  PhB: stage A(t+2)->buf (4 gll) | Q2 | load blo(t+1) (4) | Q3 |
//       load bhi(t+1) (4) | ds_read a_lo(t+1)<-nx | BAR(end)
// Issue order/tile = [A(t+2) 4][blo(t+1) 4][bhi(t+1) 4]: fixed VMCNT4/VMCNT0
// are exact in steady state and conservative-correct in tails/prologue.
// Cross-wave A publication: own A(t+1) glls drained at VMCNT4 (pre mid-BAR);
// a_lo(t+1) is read after mid-BAR by all waves. A-stage WAR: a_hi(t) read
// pre-mid-BAR, stage post-mid-BAR (R8-proven placement).
// ---------------------------------------------------------------------------
__global__ void __launch_bounds__(512, 2) gemm_kernel(
    const unsigned short* __restrict__ Ag,   // [M][K] bf16 bits (x)
    const unsigned short* __restrict__ Bg,   // [N][K] bf16 bits (adapted W)
    const float* __restrict__ bias,
    float* __restrict__ out) {
  __shared__ __attribute__((aligned(16))) unsigned short LDS[2 * 16384];  // 64KB, A only

  // Column-major bijective XCD swizzle: grid = 512, chunk 64/XCD = 2 bcols x 32 brows.
  const int nwg = gridDim.x;
  const int q8 = nwg >> 3;
  const int wg = blockIdx.x;
  const int swz = (wg & 7) * q8 + (wg >> 3);
  const int brow = (swz & 31) * 256;         // 32 row-bands
  const int bcol = (swz >> 5) * 256;         // 16 col-bands

  const int tid = threadIdx.x;
  const int lane = tid & 63;
  const int w = tid >> 6;                    // wave 0..7
  const int wr = w >> 2, wc = w & 3;         // 2 x 4 wave grid
  const int fr = lane & 15;
  const int kq = (lane >> 4) << 3;           // 0,8,16,24

  // A staging source map (inverse of st_16x32 swizzle)
  const int rr = lane >> 2;
  const int cc = ((lane & 1) << 3) | ((((lane >> 1) ^ (lane >> 5)) & 1) << 4);
  const int c_sw = ((w & 1) << 5) | cc;
  const int rbase = ((w >> 1) << 4) + rr;

  const unsigned short* srcA[2][2];          // [half][q]
#pragma unroll
  for (int h = 0; h < 2; ++h)
#pragma unroll
    for (int q = 0; q < 2; ++q)
      srcA[h][q] = Ag + (size_t)(brow + h * 128 + q * 64 + rbase) * K_DIM + c_sw;

  auto stageA = [&](int buf, int h, int kt) {  // 2 gll, 16B/lane
#pragma unroll
    for (int q = 0; q < 2; ++q)
      __builtin_amdgcn_global_load_lds(AS1(srcA[h][q] + (size_t)kt * 64),
          AS3(&LDS[buf * 16384 + h * 8192 + q * 4096 + w * 512]), 16, 0, 0);
  };

  // swizzled A ds_read addressing
  const int rdsw = ((fr << 6) | (kq << 1)) ^ ((fr & 8) << 2);
  auto lda = [&](int buf, int m, int kk) -> bf16x8 {
    return *(const bf16x8*)((const char*)LDS +
        (buf * 32768 + wr * 16384 + (m * 2 + kk) * 1024 + rdsw));
  };

  // B fragment base pointers (global, per n): row = bcol + wc*64 + n*16 + fr
  const unsigned short* bp[4];
#pragma unroll
  for (int n = 0; n < 4; ++n)
    bp[n] = Bg + (size_t)(bcol + wc * 64 + n * 16 + fr) * K_DIM + kq;

  f32x4 acc[8][4] = {};
  bf16x8 a[2][4];          // current A half (a_lo -> a_hi in-place per tile)
  bf16x8 blo[2][2], bhi[2][2];

  auto read_a = [&](int buf, int mg) {       // mg=0: a_lo, mg=4: a_hi
#pragma unroll
    for (int kk = 0; kk < 2; ++kk)
#pragma unroll
      for (int mi = 0; mi < 4; ++mi)
        a[kk][mi] = lda(buf, mg + mi, kk);
  };
  auto load_blo = [&](int t) {               // 4 x global_load_dwordx4
#pragma unroll
    for (int kk = 0; kk < 2; ++kk)
#pragma unroll
      for (int ni = 0; ni < 2; ++ni)
        blo[kk][ni] = *(const bf16x8*)(bp[ni] + (size_t)t * 64 + kk * 32);
  };
  auto load_bhi = [&](int t) {
#pragma unroll
    for (int kk = 0; kk < 2; ++kk)
#pragma unroll
      for (int ni = 0; ni < 2; ++ni)
        bhi[kk][ni] = *(const bf16x8*)(bp[2 + ni] + (size_t)t * 64 + kk * 32);
  };
  auto mma_b = [&](bf16x8 (&bb)[2][2], int am, int an) {   // 8 MFMA
#pragma unroll
    for (int mi = 0; mi < 4; ++mi)
#pragma unroll
      for (int ni = 0; ni < 2; ++ni)
#pragma unroll
        for (int kk = 0; kk < 2; ++kk)
          acc[am + mi][an + ni] = __builtin_amdgcn_mfma_f32_16x16x32_bf16(
              a[kk][mi], bb[kk][ni], acc[am + mi][an + ni], 0, 0, 0);
  };

  // one tile = 2 phases; g2: A(t+2) exists; gr: tile t+1 exists
  auto tile_body = [&](int t, int buf, bool g2, bool gr) {
    const int nxbuf = buf ^ 1;
    // Phase A
    VMCNT4();                                // blo(t) + own A(t+1) glls done
    __builtin_amdgcn_s_setprio(1); mma_b(blo, 0, 0); __builtin_amdgcn_s_setprio(0);
    VMCNT0();                                // bhi(t) done
    __builtin_amdgcn_s_setprio(1); mma_b(bhi, 0, 2); __builtin_amdgcn_s_setprio(0);
    read_a(buf, 4);                          // a_hi(t); last a_lo use was Q1
    BAR();                                   // mid: buf fully read -> stage ok
    // Phase B
    if (g2) stageA(buf, 0, t + 2), stageA(buf, 1, t + 2);
    __builtin_amdgcn_s_setprio(1); mma_b(blo, 4, 0); __builtin_amdgcn_s_setprio(0);
    if (gr) load_blo(t + 1);                 // WAR after Q2 (last blo use)
    __builtin_amdgcn_s_setprio(1); mma_b(bhi, 4, 2); __builtin_amdgcn_s_setprio(0);
    if (gr) load_bhi(t + 1);                 // WAR after Q3 (last bhi use)
    if (gr) read_a(nxbuf, 0);                // a_lo(t+1); A(t+1) published pre-mid-BAR
    BAR();                                   // end
  };

  // prologue: A(0)->buf0, A(1)->buf1 (8 gll); b(0) direct; wait A(0); pre-read a_lo(0)
  stageA(0, 0, 0); stageA(0, 1, 0);
  stageA(1, 0, 1); stageA(1, 1, 1);
  load_blo(0); load_bhi(0);
  VMCNT12();                                 // A(0) done (leaves A(1)+b(0)=12)
  BAR();
  read_a(0, 0);

  // main loop: 32 pairs of tiles (NT = 64)
#pragma unroll 1
  for (int i = 0; i < 32; ++i) {
    const bool more = (i < 31);
    tile_body(2 * i,     0, more, true);
    tile_body(2 * i + 1, 1, more, more);
  }

  // epilogue: C/D map col = lane&15, row = (lane>>4)*4 + j
  const int fq = (lane >> 4) * 4;
#pragma unroll
  for (int n = 0; n < 4; ++n) {
    const int col = bcol + wc * 64 + n * 16 + fr;
    const float bb = bias[col];
#pragma unroll
    for (int m = 0; m < 8; ++m) {
      const int row = brow + wr * 128 + m * 16 + fq;
      f32x4 v = acc[m][n];
#pragma unroll
      for (int j = 0; j < 4; ++j)
        out[(size_t)(row + j) * N_DIM + col] = v[j] + bb;
    }
  }
}

// ---------------------------------------------------------------------------
extern "C" void kernel_launch(void* const* d_in, const int* in_sizes, int n_in,
                              void* d_out, int out_size, void* d_ws, size_t ws_size,
                              hipStream_t stream) {
  const float* x    = (const float*)d_in[0];
  const float* W    = (const float*)d_in[1];
  const float* bias = (const float*)d_in[2];
  const float* lA   = (const float*)d_in[3];
  const float* lB   = (const float*)d_in[4];
  float* out = (float*)d_out;

  unsigned short* xb  = (unsigned short*)d_ws;            // 64 MiB
  unsigned short* awb = xb + (size_t)M_DIM * K_DIM;       // 32 MiB

  prep_kernel<<<1024 + CVT_BLOCKS, 256, 0, stream>>>(x, W, lA, lB, xb, awb);
  gemm_kernel<<<(M_DIM / 256) * (N_DIM / 256), 512, 0, stream>>>(xb, awb, bias, out);
}

// Round 10
// 359.839 us; speedup vs baseline: 1.3165x; 1.3165x over previous
//
#include <hip/hip_runtime.h>
#include <hip/hip_bf16.h>
#include <stdint.h>

// Problem dims: B=4, S=2048 -> M=8192; IN=K=4096; OUT=N=4096; R=16
#define M_DIM 8192
#define N_DIM 4096
#define K_DIM 4096
#define R_DIM 16

typedef __bf16 bf16x8 __attribute__((ext_vector_type(8)));
typedef float f32x4 __attribute__((ext_vector_type(4)));
typedef unsigned short u16x8 __attribute__((ext_vector_type(8)));

#define AS1(p) ((const __attribute__((address_space(1))) void*)(p))
#define AS3(p) ((__attribute__((address_space(3))) void*)(p))

#define BAR() do { asm volatile("" ::: "memory"); __builtin_amdgcn_s_barrier(); asm volatile("" ::: "memory"); } while (0)
#define VMCNT4()  asm volatile("s_waitcnt vmcnt(4)" ::: "memory")
#define VMCNT0()  asm volatile("s_waitcnt vmcnt(0)" ::: "memory")
#define VMCNT12() asm volatile("s_waitcnt vmcnt(12)" ::: "memory")

__device__ __forceinline__ unsigned short f2bf(float f) {
  unsigned u = __builtin_bit_cast(unsigned, f);
  u += 0x7FFFu + ((u >> 16) & 1u);   // round-to-nearest-even
  return (unsigned short)(u >> 16);
}

// ---------------------------------------------------------------------------
// prep: blocks [0,1024): awb_packed = bf16(W*(1+A^T B^T)) in MFMA-fragment
//       order: chunk = (o>>4)*128 + (i>>5) holds a 16(N)x32(K) fragment;
//       elem (o,i) at chunk*512 + ((i&31)>>3)*128 + (o&15)*8 + (i&7).
//       GEMM lane l then reads 16B at chunk*1024 + l*16 (perfectly coalesced).
//       blocks [1024,5120): xb = bf16(x), vectorized grid-stride
// ---------------------------------------------------------------------------
#define CVT_BLOCKS 4096
__global__ void __launch_bounds__(256) prep_kernel(
    const float* __restrict__ x, const float* __restrict__ W,
    const float* __restrict__ lA, const float* __restrict__ lB,
    unsigned short* __restrict__ xb, unsigned short* __restrict__ awb) {
  __shared__ float Asub[16 * 512];
  __shared__ float Bsub[32 * 16];
  const int tid = threadIdx.x;

  if (blockIdx.x < 1024) {
    const int i0 = (blockIdx.x & 7) * 512;
    const int o0 = (blockIdx.x >> 3) * 32;
    for (int idx = tid; idx < 16 * 512; idx += 256) {
      int r = idx >> 9, i = idx & 511;
      Asub[idx] = lA[r * K_DIM + i0 + i];
    }
    for (int idx = tid; idx < 32 * 16; idx += 256) {
      int o = idx >> 4, r = idx & 15;
      Bsub[idx] = lB[(o0 + o) * R_DIM + r];
    }
    __syncthreads();
    // 32 o x 64 groups of 8 i per block; one u16x8 packed write per iter
    for (int idx = tid; idx < 32 * 64; idx += 256) {
      const int o = idx >> 6;              // local o
      const int i8 = (idx & 63) << 3;      // local i base (multiple of 8)
      const int go = o0 + o, gi = i0 + i8;
      const float4 w0 = *(const float4*)&W[(size_t)go * K_DIM + gi];
      const float4 w1 = *(const float4*)&W[(size_t)go * K_DIM + gi + 4];
      u16x8 v;
#pragma unroll
      for (int j = 0; j < 8; ++j) {
        float s = 1.0f;
#pragma unroll
        for (int r = 0; r < 16; ++r) s += Asub[r * 512 + i8 + j] * Bsub[o * 16 + r];
        const float wj = (j < 4) ? ((const float*)&w0)[j] : ((const float*)&w1)[j - 4];
        v[j] = f2bf(wj * s);
      }
      const size_t chunk = (size_t)(go >> 4) * 128 + (gi >> 5);
      const int eoff = ((gi & 31) >> 3) * 128 + (go & 15) * 8;
      *(u16x8*)&awb[chunk * 512 + eoff] = v;
    }
  } else {
    const long total = (long)M_DIM * K_DIM;
    long i = ((long)(blockIdx.x - 1024) * 256 + tid) * 8;
    const long stride = (long)CVT_BLOCKS * 256 * 8;
    for (; i < total; i += stride) {
      const float4* p = (const float4*)(x + i);
      float4 f0 = p[0], f1 = p[1];
      u16x8 v;
      v[0] = f2bf(f0.x); v[1] = f2bf(f0.y); v[2] = f2bf(f0.z); v[3] = f2bf(f0.w);
      v[4] = f2bf(f1.x); v[5] = f2bf(f1.y); v[6] = f2bf(f1.z); v[7] = f2bf(f1.w);
      *(u16x8*)(xb + i) = v;
    }
  }
}

// ---------------------------------------------------------------------------
// GEMM: out[m,n] = sum_k xb[m,k]*awb[n,k] + bias[n]
// 256x256 tile, BK=64, 8 waves (2Mx4N). R9 schedule (proven correct) with
// PACKED B: fragments load global->VGPR as one coalesced dwordx4/lane from
// the fragment-ordered awb (see prep). LDS carries A only (64KB dbuf):
// 128KB reads + 32KB gll writes ~1900cy < MFMA 2060cy per K-tile -- the
// R3-R8 LDS oversubscription (256KB > MFMA) is gone, and unlike R9 the B
// loads are now single-line coalesced + L2-resident (col-major XCD swizzle:
// B working set ~4MB/XCD).
// Per tile t (buf=t&1, nx=buf^1; Q0:a_lo*blo Q1:a_lo*bhi Q2:a_hi*blo Q3:a_hi*bhi):
//  PhA: VMCNT4 [drains blo(t)+own A(t+1); leaves bhi(t)=4] | Q0 | VMCNT0 | Q1 |
//       ds_read a_hi(t) | BAR(mid)
//  PhB: stage A(t+2) (4 gll) | Q2 | load blo(t+1) (4) | Q3 | load bhi(t+1) (4) |
//       ds_read a_lo(t+1) | BAR(end)
// vmcnt FIFO/tile = [A(t+2) 4][blo(t+1) 4][bhi(t+1) 4]; fixed VMCNT4/VMCNT0
// exact in steady state, conservative-correct in tails (R9-verified).
// ---------------------------------------------------------------------------
__global__ void __launch_bounds__(512, 2) gemm_kernel(
    const unsigned short* __restrict__ Ag,   // [M][K] bf16 bits (x)
    const unsigned short* __restrict__ Bp,   // packed awb fragments
    const float* __restrict__ bias,
    float* __restrict__ out) {
  __shared__ __attribute__((aligned(16))) unsigned short LDS[2 * 16384];  // 64KB, A only

  // Column-major bijective XCD swizzle: grid = 512, 64 blocks/XCD chunk.
  const int nwg = gridDim.x;
  const int q8 = nwg >> 3;
  const int wg = blockIdx.x;
  const int swz = (wg & 7) * q8 + (wg >> 3);
  const int brow = (swz & 31) * 256;         // 32 row-bands (fast)
  const int bcol = (swz >> 5) * 256;         // 16 col-bands (slow)

  const int tid = threadIdx.x;
  const int lane = tid & 63;
  const int w = tid >> 6;                    // wave 0..7
  const int wr = w >> 2, wc = w & 3;         // 2 x 4 wave grid
  const int fr = lane & 15;
  const int kq = (lane >> 4) << 3;           // 0,8,16,24

  // A staging source map (inverse of st_16x32 swizzle)
  const int rr = lane >> 2;
  const int cc = ((lane & 1) << 3) | ((((lane >> 1) ^ (lane >> 5)) & 1) << 4);
  const int c_sw = ((w & 1) << 5) | cc;
  const int rbase = ((w >> 1) << 4) + rr;

  const unsigned short* srcA[2][2];          // [half][q]
#pragma unroll
  for (int h = 0; h < 2; ++h)
#pragma unroll
    for (int q = 0; q < 2; ++q)
      srcA[h][q] = Ag + (size_t)(brow + h * 128 + q * 64 + rbase) * K_DIM + c_sw;

  auto stageA = [&](int buf, int h, int kt) {  // 2 gll, 16B/lane
#pragma unroll
    for (int q = 0; q < 2; ++q)
      __builtin_amdgcn_global_load_lds(AS1(srcA[h][q] + (size_t)kt * 64),
          AS3(&LDS[buf * 16384 + h * 8192 + q * 4096 + w * 512]), 16, 0, 0);
  };

  // swizzled A ds_read addressing
  const int rdsw = ((fr << 6) | (kq << 1)) ^ ((fr & 8) << 2);
  auto lda = [&](int buf, int m, int kk) -> bf16x8 {
    return *(const bf16x8*)((const char*)LDS +
        (buf * 32768 + wr * 16384 + (m * 2 + kk) * 1024 + rdsw));
  };

  // Packed-B fragment pointers: n_tile = bcol/16 + wc*4 + n; chunk = n_tile*128
  // + (2t+kk); per-lane 16B at chunk*1024 + lane*16.
  const unsigned short* bp[4];
#pragma unroll
  for (int n = 0; n < 4; ++n)
    bp[n] = Bp + ((size_t)((bcol >> 4) + wc * 4 + n) * 128) * 512 + lane * 8;

  f32x4 acc[8][4] = {};
  bf16x8 a[2][4];          // current A half (a_lo -> a_hi in-place per tile)
  bf16x8 blo[2][2], bhi[2][2];

  auto read_a = [&](int buf, int mg) {       // mg=0: a_lo, mg=4: a_hi
#pragma unroll
    for (int kk = 0; kk < 2; ++kk)
#pragma unroll
      for (int mi = 0; mi < 4; ++mi)
        a[kk][mi] = lda(buf, mg + mi, kk);
  };
  auto load_blo = [&](int t) {               // 4 x coalesced global_load_dwordx4
#pragma unroll
    for (int kk = 0; kk < 2; ++kk)
#pragma unroll
      for (int ni = 0; ni < 2; ++ni)
        blo[kk][ni] = *(const bf16x8*)(bp[ni] + (size_t)(2 * t + kk) * 512);
  };
  auto load_bhi = [&](int t) {
#pragma unroll
    for (int kk = 0; kk < 2; ++kk)
#pragma unroll
      for (int ni = 0; ni < 2; ++ni)
        bhi[kk][ni] = *(const bf16x8*)(bp[2 + ni] + (size_t)(2 * t + kk) * 512);
  };
  auto mma_b = [&](bf16x8 (&bb)[2][2], int am, int an) {   // 8 MFMA
#pragma unroll
    for (int mi = 0; mi < 4; ++mi)
#pragma unroll
      for (int ni = 0; ni < 2; ++ni)
#pragma unroll
        for (int kk = 0; kk < 2; ++kk)
          acc[am + mi][an + ni] = __builtin_amdgcn_mfma_f32_16x16x32_bf16(
              a[kk][mi], bb[kk][ni], acc[am + mi][an + ni], 0, 0, 0);
  };

  // one tile = 2 phases; g2: A(t+2) exists; gr: tile t+1 exists
  auto tile_body = [&](int t, int buf, bool g2, bool gr) {
    const int nxbuf = buf ^ 1;
    // Phase A
    VMCNT4();                                // blo(t) + own A(t+1) glls done
    __builtin_amdgcn_s_setprio(1); mma_b(blo, 0, 0); __builtin_amdgcn_s_setprio(0);
    VMCNT0();                                // bhi(t) done
    __builtin_amdgcn_s_setprio(1); mma_b(bhi, 0, 2); __builtin_amdgcn_s_setprio(0);
    read_a(buf, 4);                          // a_hi(t); last a_lo use was Q1
    BAR();                                   // mid: buf fully read -> stage ok
    // Phase B
    if (g2) stageA(buf, 0, t + 2), stageA(buf, 1, t + 2);
    __builtin_amdgcn_s_setprio(1); mma_b(blo, 4, 0); __builtin_amdgcn_s_setprio(0);
    if (gr) load_blo(t + 1);                 // WAR after Q2 (last blo use)
    __builtin_amdgcn_s_setprio(1); mma_b(bhi, 4, 2); __builtin_amdgcn_s_setprio(0);
    if (gr) load_bhi(t + 1);                 // WAR after Q3 (last bhi use)
    if (gr) read_a(nxbuf, 0);                // a_lo(t+1); A(t+1) published pre-mid-BAR
    BAR();                                   // end
  };

  // prologue: A(0)->buf0, A(1)->buf1 (8 gll); b(0) direct; wait A(0); pre-read a_lo(0)
  stageA(0, 0, 0); stageA(0, 1, 0);
  stageA(1, 0, 1); stageA(1, 1, 1);
  load_blo(0); load_bhi(0);
  VMCNT12();                                 // A(0) done (leaves A(1)+b(0)=12)
  BAR();
  read_a(0, 0);

  // main loop: 32 pairs of tiles (NT = 64)
#pragma unroll 1
  for (int i = 0; i < 32; ++i) {
    const bool more = (i < 31);
    tile_body(2 * i,     0, more, true);
    tile_body(2 * i + 1, 1, more, more);
  }

  // epilogue: C/D map col = lane&15, row = (lane>>4)*4 + j
  const int fq = (lane >> 4) * 4;
#pragma unroll
  for (int n = 0; n < 4; ++n) {
    const int col = bcol + wc * 64 + n * 16 + fr;
    const float bb = bias[col];
#pragma unroll
    for (int m = 0; m < 8; ++m) {
      const int row = brow + wr * 128 + m * 16 + fq;
      f32x4 v = acc[m][n];
#pragma unroll
      for (int j = 0; j < 4; ++j)
        out[(size_t)(row + j) * N_DIM + col] = v[j] + bb;
    }
  }
}

// ---------------------------------------------------------------------------
extern "C" void kernel_launch(void* const* d_in, const int* in_sizes, int n_in,
                              void* d_out, int out_size, void* d_ws, size_t ws_size,
                              hipStream_t stream) {
  const float* x    = (const float*)d_in[0];
  const float* W    = (const float*)d_in[1];
  const float* bias = (const float*)d_in[2];
  const float* lA   = (const float*)d_in[3];
  const float* lB   = (const float*)d_in[4];
  float* out = (float*)d_out;

  unsigned short* xb  = (unsigned short*)d_ws;            // 64 MiB
  unsigned short* awb = xb + (size_t)M_DIM * K_DIM;       // 32 MiB (packed)

  prep_kernel<<<1024 + CVT_BLOCKS, 256, 0, stream>>>(x, W, lA, lB, xb, awb);
  gemm_kernel<<<(M_DIM / 256) * (N_DIM / 256), 512, 0, stream>>>(xb, awb, bias, out);
}

// Round 11
// 332.441 us; speedup vs baseline: 1.4250x; 1.0824x over previous
//
#include <hip/hip_runtime.h>
#include <hip/hip_bf16.h>
#include <stdint.h>

// Problem dims: B=4, S=2048 -> M=8192; IN=K=4096; OUT=N=4096; R=16
#define M_DIM 8192
#define N_DIM 4096
#define K_DIM 4096
#define R_DIM 16
#define NT    (K_DIM / 64)   // 64 K-tiles of BK=64

typedef __bf16 bf16x8 __attribute__((ext_vector_type(8)));
typedef float f32x16 __attribute__((ext_vector_type(16)));
typedef unsigned short u16x8 __attribute__((ext_vector_type(8)));

#define AS1(p) ((const __attribute__((address_space(1))) void*)(p))
#define AS3(p) ((__attribute__((address_space(3))) void*)(p))

// R4/R8-style macros (empirically fastest across R3-R10 variants).
#define BAR() do { asm volatile("" ::: "memory"); __builtin_amdgcn_s_barrier(); asm volatile("" ::: "memory"); } while (0)
#define VMCNT2() asm volatile("s_waitcnt vmcnt(2)" ::: "memory")
#define VMCNT0() asm volatile("s_waitcnt vmcnt(0)" ::: "memory")
#define VMCNT8() asm volatile("s_waitcnt vmcnt(8)" ::: "memory")

__device__ __forceinline__ unsigned short f2bf(float f) {
  unsigned u = __builtin_bit_cast(unsigned, f);
  u += 0x7FFFu + ((u >> 16) & 1u);   // round-to-nearest-even
  return (unsigned short)(u >> 16);
}

// ---------------------------------------------------------------------------
// prep (R8 version, row-major awb): blocks [0,1024): awb = bf16(W*(1+A^T B^T))
//       blocks [1024,5120): xb = bf16(x)
// ---------------------------------------------------------------------------
#define CVT_BLOCKS 4096
__global__ void __launch_bounds__(256) prep_kernel(
    const float* __restrict__ x, const float* __restrict__ W,
    const float* __restrict__ lA, const float* __restrict__ lB,
    unsigned short* __restrict__ xb, unsigned short* __restrict__ awb) {
  __shared__ float Asub[16 * 512];
  __shared__ float Bsub[32 * 16];
  const int tid = threadIdx.x;

  if (blockIdx.x < 1024) {
    const int i0 = (blockIdx.x & 7) * 512;
    const int o0 = (blockIdx.x >> 3) * 32;
    for (int idx = tid; idx < 16 * 512; idx += 256) {
      int r = idx >> 9, i = idx & 511;
      Asub[idx] = lA[r * K_DIM + i0 + i];
    }
    for (int idx = tid; idx < 32 * 16; idx += 256) {
      int o = idx >> 4, r = idx & 15;
      Bsub[idx] = lB[(o0 + o) * R_DIM + r];
    }
    __syncthreads();
    for (int idx = tid; idx < 32 * 512; idx += 256) {
      int o = idx >> 9, i = idx & 511;
      float s = 1.0f;
#pragma unroll
      for (int r = 0; r < 16; ++r) s += Asub[r * 512 + i] * Bsub[o * 16 + r];
      size_t g = (size_t)(o0 + o) * K_DIM + i0 + i;
      awb[g] = f2bf(W[g] * s);
    }
  } else {
    const long total = (long)M_DIM * K_DIM;
    long i = ((long)(blockIdx.x - 1024) * 256 + tid) * 8;
    const long stride = (long)CVT_BLOCKS * 256 * 8;
    for (; i < total; i += stride) {
      const float4* p = (const float4*)(x + i);
      float4 f0 = p[0], f1 = p[1];
      u16x8 v;
      v[0] = f2bf(f0.x); v[1] = f2bf(f0.y); v[2] = f2bf(f0.z); v[3] = f2bf(f0.w);
      v[4] = f2bf(f1.x); v[5] = f2bf(f1.y); v[6] = f2bf(f1.z); v[7] = f2bf(f1.w);
      *(u16x8*)(xb + i) = v;
    }
  }
}

// ---------------------------------------------------------------------------
// GEMM: out[m,n] = sum_k xb[m,k]*awb[n,k] + bias[n]
// 256x256 tile, BK=64, 8 waves (2Mx4N), per-wave 128x64 via 32x32x16 MFMA:
// acc f32x16[4 mi][2 ni] = 128 regs; 32 MFMA/wave/tile (vs 64 with 16x16) at
// 4060 FLOP/cy (vs 3380) -> MFMA term 2483->2046 cy/tile, halved MFMA issue
// pressure. Both operands via LDS (B-direct refuted R9/R10). R8 schedule:
//  PhA(t): stage B kg01(t+2) | mma kk01(t) | ds_read kk23(t) | VMCNT2 | BAR
//  PhB(t): stage B kg23 + A kg0-3 (t+2) | mma kk23(t) | ds_read kk01(t+1) | BAR
// vmcnt FIFO at PhA(t): [t+1: 8][B01(t+2): 2] -> VMCNT2 completes all of t+1
// before PhB(t) reads it (R8-identical ledger; all stage targets >=1 barrier
// past their last read).
// LDS subtile = 32 rows x 16 k = 1KB; elem (r,k) at byte
//   (r&15)*64 + ((r>>4)*2 + (k>>3))*16 + (k&7)*2
// -> gll linear write (lane*16B) fetches global row=(lane>>1&1)*16+(lane>>2),
//    k=(lane&1)*8 (contiguous 16B; the 4 k-group issues consume full lines);
// -> frag ds_read: lane reads 16B at (lane&15)*64 + ((lane>>4&1)*2+(lane>>5))*16
//    = A[row=lane&31][k=(lane>>5)*8+e] (MFMA A/B operand layout); each
//    bank-quad claimed exactly 8x = the b128 structural minimum (no conflicts).
// C/D map (m74/m101): col=lane&31, row=(reg&3)+8*(reg>>2)+4*(lane>>5).
// ---------------------------------------------------------------------------
__global__ void __launch_bounds__(512, 2) gemm_kernel(
    const unsigned short* __restrict__ Ag,   // [M][K] bf16 bits (x)
    const unsigned short* __restrict__ Bg,   // [N][K] bf16 bits (adapted W)
    const float* __restrict__ bias,
    float* __restrict__ out) {
  __shared__ __attribute__((aligned(16))) char LDSc[2 * 65536];  // 128KB

  // Bijective XCD swizzle (row-major, R8's proven locality): grid = 512.
  const int nwg = gridDim.x;
  const int q8 = nwg >> 3;
  const int wg = blockIdx.x;
  const int swz = (wg & 7) * q8 + (wg >> 3);
  const int tiles_n = N_DIM / 256;           // 16
  const int brow = (swz / tiles_n) * 256;
  const int bcol = (swz % tiles_n) * 256;

  const int tid = threadIdx.x;
  const int lane = tid & 63;
  const int w = tid >> 6;                    // wave 0..7
  const int wr = w >> 2, wc = w & 3;         // 2M x 4N wave grid

  // gll source map (inverse of subtile layout; see header comment)
  const int grow = ((lane >> 1) & 1) * 16 + (lane >> 2);
  const int gcol = (lane & 1) * 8;

  const unsigned short* srcAbase = Ag + (size_t)(brow + w * 32 + grow) * K_DIM + gcol;
  const unsigned short* srcBbase = Bg + (size_t)(bcol + w * 32 + grow) * K_DIM + gcol;

  // A k-group j of buf at bytes [buf*65536 + w*4096 + j*1024]; B at +32768.
  auto stageA4 = [&](int buf, int kt) {      // 4 gll (k-groups 0..3)
#pragma unroll
    for (int j = 0; j < 4; ++j)
      __builtin_amdgcn_global_load_lds(AS1(srcAbase + (size_t)kt * 64 + j * 16),
          AS3(LDSc + buf * 65536 + w * 4096 + j * 1024), 16, 0, 0);
  };
  auto stageB2 = [&](int buf, int kt, int j0) {  // 2 gll (k-groups j0, j0+1)
#pragma unroll
    for (int j = 0; j < 2; ++j)
      __builtin_amdgcn_global_load_lds(AS1(srcBbase + (size_t)kt * 64 + (j0 + j) * 16),
          AS3(LDSc + buf * 65536 + 32768 + w * 4096 + (j0 + j) * 1024), 16, 0, 0);
  };

  // frag ds_read lane offset within a 1KB subtile
  const int loff = (lane & 15) * 64 + (((lane >> 4) & 1) * 2 + (lane >> 5)) * 16;

  f32x16 acc[4][2] = {};
  bf16x8 a[2][4], b[2][2];   // one kk-half live at a time (j = kk&1)

  auto read_half = [&](int buf, int half) {  // 12 x ds_read_b128
#pragma unroll
    for (int j = 0; j < 2; ++j)
#pragma unroll
      for (int mi = 0; mi < 4; ++mi)
        a[j][mi] = *(const bf16x8*)(LDSc + buf * 65536 +
            (wr * 4 + mi) * 4096 + (half * 2 + j) * 1024 + loff);
#pragma unroll
    for (int j = 0; j < 2; ++j)
#pragma unroll
      for (int ni = 0; ni < 2; ++ni)
        b[j][ni] = *(const bf16x8*)(LDSc + buf * 65536 + 32768 +
            (wc * 2 + ni) * 4096 + (half * 2 + j) * 1024 + loff);
  };
  auto mma_half = [&]() {                    // 16 x mfma_32x32x16
#pragma unroll
    for (int mi = 0; mi < 4; ++mi)
#pragma unroll
      for (int ni = 0; ni < 2; ++ni)
#pragma unroll
        for (int j = 0; j < 2; ++j)
          acc[mi][ni] = __builtin_amdgcn_mfma_f32_32x32x16_bf16(
              a[j][mi], b[j][ni], acc[mi][ni], 0, 0, 0);
  };

  // one tile = 2 phases; g2: tile t+2 exists; gr: tile t+1 exists
  auto tile_body = [&](int t, int buf, bool g2, bool gr) {
    const int nxbuf = buf ^ 1;
    // Phase A
    if (g2) stageB2(buf, t + 2, 0);
    __builtin_amdgcn_s_setprio(1); mma_half(); __builtin_amdgcn_s_setprio(0);
    read_half(buf, 1);                       // kk23(t); WAR after kk01's last use
    if (g2) { VMCNT2(); } else { VMCNT0(); } // publishes all of tile t+1
    BAR();                                   // mid
    // Phase B
    if (g2) { stageB2(buf, t + 2, 2); stageA4(buf, t + 2); }
    __builtin_amdgcn_s_setprio(1); mma_half(); __builtin_amdgcn_s_setprio(0);
    if (gr) read_half(nxbuf, 0);             // kk01(t+1)
    BAR();                                   // end
  };

  // prologue: tile0 -> buf0 (8 gll), tile1 -> buf1 (8 gll); drain t0; pre-read
  stageB2(0, 0, 0); stageB2(0, 0, 2); stageA4(0, 0);
  stageB2(1, 1, 0); stageB2(1, 1, 2); stageA4(1, 1);
  VMCNT8();
  BAR();
  read_half(0, 0);

  // main loop: 32 pairs of tiles (NT = 64)
#pragma unroll 1
  for (int i = 0; i < 32; ++i) {
    const bool more = (i < 31);
    tile_body(2 * i,     0, more, true);
    tile_body(2 * i + 1, 1, more, more);
  }

  // epilogue: col = lane&31, row = (reg&3) + 8*(reg>>2) + 4*(lane>>5)
  const int c32 = lane & 31;
  const int r4 = (lane >> 5) * 4;
#pragma unroll
  for (int ni = 0; ni < 2; ++ni) {
    const int col = bcol + wc * 64 + ni * 32 + c32;
    const float bb = bias[col];
#pragma unroll
    for (int mi = 0; mi < 4; ++mi) {
      const int rowbase = brow + wr * 128 + mi * 32 + r4;
      f32x16 v = acc[mi][ni];
#pragma unroll
      for (int reg = 0; reg < 16; ++reg) {
        const int row = rowbase + (reg & 3) + 8 * (reg >> 2);
        out[(size_t)row * N_DIM + col] = v[reg] + bb;
      }
    }
  }
}

// ---------------------------------------------------------------------------
extern "C" void kernel_launch(void* const* d_in, const int* in_sizes, int n_in,
                              void* d_out, int out_size, void* d_ws, size_t ws_size,
                              hipStream_t stream) {
  const float* x    = (const float*)d_in[0];
  const float* W    = (const float*)d_in[1];
  const float* bias = (const float*)d_in[2];
  const float* lA   = (const float*)d_in[3];
  const float* lB   = (const float*)d_in[4];
  float* out = (float*)d_out;

  unsigned short* xb  = (unsigned short*)d_ws;            // 64 MiB
  unsigned short* awb = xb + (size_t)M_DIM * K_DIM;       // 32 MiB

  prep_kernel<<<1024 + CVT_BLOCKS, 256, 0, stream>>>(x, W, lA, lB, xb, awb);
  gemm_kernel<<<(M_DIM / 256) * (N_DIM / 256), 512, 0, stream>>>(xb, awb, bias, out);
}